// Round 14
// baseline (1472.400 us; speedup 1.0000x reference)
//
#include <hip/hip_runtime.h>
#include <hip/hip_cooperative_groups.h>
#include <math.h>

namespace cg = cooperative_groups;

#define B_ 64
#define T_ 128
#define I_ 1024
#define H_ 4096
#define XCDS 8

#define RNN_BLOCKS 256
#define RNN_THREADS 1024

#define MAXIT_IH 8    // 64 nnz/row registerized (Poisson(32)); tail fallback beyond

// ---------------- helpers ----------------
__device__ __forceinline__ unsigned short f2bf(float f) {
    unsigned int u = __float_as_uint(f);
    unsigned int r = (u + 0x7fffu + ((u >> 16) & 1u)) >> 16;
    return (unsigned short)r;
}

__device__ __forceinline__ void load2x16_sc0(const void* p0, const void* p1,
                                             uint4& a, uint4& b) {
    asm volatile(
        "global_load_dwordx4 %0, %2, off sc0\n\t"
        "global_load_dwordx4 %1, %3, off sc0\n\t"
        "s_waitcnt vmcnt(0)"
        : "=&v"(a), "=&v"(b)
        : "v"(p0), "v"(p1));
}

// ---------------- transpose x (B,T,I) -> xT2 (T, 8, I, 8) bf16 ----------------
__global__ void transpose_x(const float* __restrict__ x, unsigned short* __restrict__ xT2) {
    __shared__ float lds[8][129];
    int t  = blockIdx.z;
    int bg = blockIdx.y;
    int i0 = blockIdx.x * 128;
    int tx = threadIdx.x;   // 0..127
    int ty = threadIdx.y;   // 0..7
    int b = bg * 8 + ty;
    lds[ty][tx] = x[(size_t)b * T_ * I_ + (size_t)t * I_ + i0 + tx];
    __syncthreads();
    int n  = ty * 128 + tx;
    int ii = n >> 3;
    int bs = n & 7;
    xT2[(((size_t)t * 8 + bg) * I_ + i0 + ii) * 8 + bs] = f2bf(lds[bs][ii]);
}

// ---------------- CSR build ----------------
__global__ void hist_rows(const int* __restrict__ rows, int nnz, int* __restrict__ counts) {
    int k = blockIdx.x * blockDim.x + threadIdx.x;
    if (k < nnz) atomicAdd(&counts[rows[k]], 1);
}

// pad each group-of-8 rows to (group max rounded up to 8): uniform len, no guards
__global__ void pad_counts(const int* __restrict__ cnt, int* __restrict__ pcnt) {
    int grp = blockIdx.x * blockDim.x + threadIdx.x;
    if (grp >= H_ / 8) return;
    int m = 0;
    #pragma unroll
    for (int j = 0; j < 8; ++j) m = max(m, cnt[grp * 8 + j]);
    m = (m + 7) & ~7;
    #pragma unroll
    for (int j = 0; j < 8; ++j) pcnt[grp * 8 + j] = m;
}

__global__ void scan_rows(const int* __restrict__ counts, int* __restrict__ rp, int n) {
    int lane = threadIdx.x;      // 0..63
    int chunk = n / 64;
    int base = lane * chunk;
    int s = 0;
    for (int j = 0; j < chunk; ++j) s += counts[base + j];
    int pre = s;
    for (int off = 1; off < 64; off <<= 1) {
        int up = __shfl_up(pre, off, 64);
        if (lane >= off) pre += up;
    }
    int run = pre - s;
    for (int j = 0; j < chunk; ++j) { rp[base + j] = run; run += counts[base + j]; }
    if (lane == 63) rp[n] = run;
}

__global__ void scatter_pack(const int* __restrict__ rows, const int* __restrict__ cols,
                             const float* __restrict__ vals, int nnz,
                             const int* __restrict__ rp, int* __restrict__ cursor,
                             int2* __restrict__ pack) {
    int k = blockIdx.x * blockDim.x + threadIdx.x;
    if (k < nnz) {
        int r = rows[k];
        int pos = atomicAdd(&cursor[r], 1);
        pack[rp[r] + pos] = make_int2(cols[k], __float_as_int(vals[k]));
    }
}

// ---------------- kernel P: pre[t] = W_ih * x_t + bias  (bf16 out) ----------------
// r12 proven form: bf16 x, 16 waves share double-buffered staging,
// issue-early/write-late, one barrier/step, CSR slice registerized.
__global__ __launch_bounds__(1024)
void precompute_ih(const unsigned short* __restrict__ xT2,
                   const int* __restrict__ rp, const int2* __restrict__ pack,
                   const float* __restrict__ bias,
                   unsigned short* __restrict__ pre) {
    __shared__ __align__(16) unsigned short xs[2][I_ * 8];   // 2 x 16 KB double buffer
    int grp  = blockIdx.y;
    int wave = threadIdx.x >> 6;                  // 0..15
    int lane = threadIdx.x & 63;
    int rs = lane >> 3;   // row within group
    int u  = lane & 7;    // position within window

    int g = blockIdx.x * 16 + wave;               // 0..511
    int r = g * 8 + rs;
    int hb = rp[r];
    int len = rp[r + 1] - hb;
    int lm = len;
    lm = max(lm, __shfl_xor(lm, 8));
    lm = max(lm, __shfl_xor(lm, 16));
    lm = max(lm, __shfl_xor(lm, 32));
    int lmax = __builtin_amdgcn_readfirstlane(lm);
    float bsv = bias[r];

    // registerize the CSR slice (t-invariant): byte offsets pre-shifted
    int   pcol[MAXIT_IH];
    float pval[MAXIT_IH];
    #pragma unroll
    for (int it = 0; it < MAXIT_IH; ++it) {
        int2 pk = make_int2(0, 0);
        if (it * 8 + u < len) pk = pack[hb + it * 8 + u];
        pcol[it] = pk.x << 4;                 // col * 8 bf16 * 2 B
        pval[it] = __int_as_float(pk.y);
    }

    // prologue: stage t=0 into buffer 0
    {
        const uint4* s = (const uint4*)(xT2 + ((size_t)0 * 8 + grp) * (I_ * 8));
        ((uint4*)xs[0])[threadIdx.x] = s[threadIdx.x];   // 1024 x 16 B = 16 KB
    }
    __syncthreads();

    for (int t = 0; t < T_; ++t) {
        int cur = t & 1;

        // issue next step's staging load early (latency hides under compute)
        uint4 st0;
        bool havenext = (t + 1 < T_);
        if (havenext) {
            const uint4* s = (const uint4*)(xT2 + ((size_t)(t + 1) * 8 + grp) * (I_ * 8));
            st0 = s[threadIdx.x];
        }

        const char* xb = (const char*)xs[cur];
        float a[8];
        #pragma unroll
        for (int j = 0; j < 8; ++j) a[j] = 0.0f;

        // branchless registerized windows (padded lanes read col 0, add +0.0)
        #pragma unroll
        for (int it = 0; it < MAXIT_IH; ++it) {
            uint4 xw = *(const uint4*)(xb + pcol[it]);
            float v = pval[it];
            a[0] += v * __uint_as_float(xw.x << 16);
            a[1] += v * __uint_as_float(xw.x & 0xffff0000u);
            a[2] += v * __uint_as_float(xw.y << 16);
            a[3] += v * __uint_as_float(xw.y & 0xffff0000u);
            a[4] += v * __uint_as_float(xw.z << 16);
            a[5] += v * __uint_as_float(xw.z & 0xffff0000u);
            a[6] += v * __uint_as_float(xw.w << 16);
            a[7] += v * __uint_as_float(xw.w & 0xffff0000u);
        }
        if (lmax > 8 * MAXIT_IH) {   // rare tail, same summation order
            int kk = hb + 8 * MAXIT_IH + u;
            for (int i = 8 * MAXIT_IH; i < lmax; i += 8, kk += 8) {
                int2 pk = make_int2(0, 0);
                if (i + u < len) pk = pack[kk];
                uint4 xw = *(const uint4*)(xb + ((size_t)pk.x << 4));
                float v = __int_as_float(pk.y);
                a[0] += v * __uint_as_float(xw.x << 16);
                a[1] += v * __uint_as_float(xw.x & 0xffff0000u);
                a[2] += v * __uint_as_float(xw.y << 16);
                a[3] += v * __uint_as_float(xw.y & 0xffff0000u);
                a[4] += v * __uint_as_float(xw.z << 16);
                a[5] += v * __uint_as_float(xw.z & 0xffff0000u);
                a[6] += v * __uint_as_float(xw.w << 16);
                a[7] += v * __uint_as_float(xw.w & 0xffff0000u);
            }
        }
        #pragma unroll
        for (int off = 1; off <= 4; off <<= 1) {
            #pragma unroll
            for (int j = 0; j < 8; ++j) a[j] += __shfl_xor(a[j], off);
        }
        float sel = (u == 0) ? a[0] : (u == 1) ? a[1] : (u == 2) ? a[2] : (u == 3) ? a[3]
                  : (u == 4) ? a[4] : (u == 5) ? a[5] : (u == 6) ? a[6] : a[7];
        float p = sel + bsv;
        int hf = u >> 2, cc = u & 3;
        pre[((size_t)(grp * 2 + hf) * T_ + t) * (H_ * 4) + (size_t)r * 4 + cc] = f2bf(p);

        // write-late: commit next step's staging to the other buffer
        if (havenext) {
            ((uint4*)xs[cur ^ 1])[threadIdx.x] = st0;
        }
        __syncthreads();   // xs[cur^1] published; readers of xs[cur] done
    }
}

// ---------------- kernel R: persistent XCD-local recurrence ----------------
// r12 structure (bf16 state, padded guard-free CSR, 1-deep hhpack prefetch,
// early pre load). ONLY delta vs r12: XCD barrier via per-block padded
// arrival slots (plain store, 64B apart -> parallel commit, no RMW
// serialization) + parallel per-lane polling (lane j polls slot j; single
// propagation hop, no master). Deadlock-free: every block stores its
// monotone generation before any block's poll can require it.
// hg layout: hg[((grp*2 + parity)*2 + half) * (H_*4)]  (ushort elements)
__global__ __launch_bounds__(RNN_THREADS, 1)
void rnn_steps(const int* __restrict__ hhp, const int2* __restrict__ hhpack,
               const unsigned short* __restrict__ pre,
               unsigned short* __restrict__ hg,
               int* __restrict__ regcnt, int* __restrict__ barcnt, int* __restrict__ bargen,
               int* __restrict__ owncnt, int* __restrict__ owngrp,
               int* __restrict__ arrive,
               float* __restrict__ out) {
    cg::grid_group grid = cg::this_grid();
    __shared__ __align__(16) unsigned short sh[H_ * 4];   // 32 KB: bf16 h_prev
    __shared__ int meta[2];

    int tid = threadIdx.x;
    if (tid == 0) {
        int x;
        asm volatile("s_getreg_b32 %0, hwreg(HW_REG_XCC_ID)" : "=s"(x));
        x &= 7;
        int slot = __hip_atomic_fetch_add(&regcnt[x], 1, __ATOMIC_RELAXED,
                                          __HIP_MEMORY_SCOPE_AGENT);
        meta[0] = x;
        meta[1] = slot;
    }
    __syncthreads();
    int xcd  = meta[0];
    int slot = meta[1];
    grid.sync();

    if (blockIdx.x == 0 && tid == 0) {
        int list[XCDS]; int nz = 0;
        for (int j = 0; j < XCDS; ++j) {
            owncnt[j] = 0;
            if (__hip_atomic_load(&regcnt[j], __ATOMIC_RELAXED,
                                  __HIP_MEMORY_SCOPE_AGENT) > 0) list[nz++] = j;
        }
        int rr = 0;
        for (int j = 0; j < XCDS; ++j) {
            int present = __hip_atomic_load(&regcnt[j], __ATOMIC_RELAXED,
                                            __HIP_MEMORY_SCOPE_AGENT) > 0;
            int owner = present ? j : list[rr++ % nz];
            owngrp[owner * 8 + owncnt[owner]] = j;
            owncnt[owner] += 1;
        }
    }
    grid.sync();

    int nblk = __hip_atomic_load(&regcnt[xcd], __ATOMIC_RELAXED, __HIP_MEMORY_SCOPE_AGENT);
    int nown = owncnt[xcd];

    int wave = tid >> 6;
    int lane = tid & 63;
    int rs   = lane >> 3;
    int u    = lane & 7;

    // half assignment (robust to nblk==1)
    int hfbeg, hfend, mywave, nwh;
    if (nblk >= 2) {
        int hf = slot & 1;
        hfbeg = hf; hfend = hf + 1;
        int nhb = (hf == 0) ? ((nblk + 1) >> 1) : (nblk >> 1);
        mywave = (slot >> 1) * (RNN_THREADS / 64) + wave;
        nwh = nhb * (RNN_THREADS / 64);
    } else {
        hfbeg = 0; hfend = 2;
        mywave = wave; nwh = RNN_THREADS / 64;
    }

    // arrival slots: 16 ints (64 B) apart to avoid same-line store serialization
    int* myarr   = &arrive[xcd * 1024 + slot * 16];
    int* arrbase = &arrive[xcd * 1024];

    for (int t = 0; t < T_; ++t) {
        for (int oi = 0; oi < nown; ++oi) {
            int grp = owngrp[xcd * 8 + oi];
            for (int hf = hfbeg; hf < hfend; ++hf) {
                const unsigned short* src =
                    hg + (size_t)((grp * 2 + (t & 1)) * 2 + hf) * (H_ * 4);
                unsigned short* dst =
                    hg + (size_t)((grp * 2 + ((t + 1) & 1)) * 2 + hf) * (H_ * 4);

                // ---- fill sh with bf16 h_prev (sc0: bypass stale L1, hit L2) ----
                __syncthreads();   // prior readers of sh are done
                {
                    uint4 v0, v1;
                    const char* s = (const char*)src;
                    load2x16_sc0(s + (size_t)tid * 16,
                                 s + (size_t)(1024 + tid) * 16, v0, v1);
                    uint4* s4 = (uint4*)sh;
                    s4[tid]        = v0;
                    s4[1024 + tid] = v1;
                }
                __syncthreads();   // sh ready

                // ---- compute: hh SpMM rows + pre + tanh (guard-free padded CSR) ----
                for (int g = mywave; g < H_ / 8; g += nwh) {
                    int r  = g * 8 + rs;
                    int hb = hhp[r];
                    int len = hhp[r + 1] - hb;   // padded: uniform across group

                    // early pre load (u<8 index safe; consumed after reduce)
                    unsigned short pus =
                        pre[((size_t)(grp * 2 + hf) * T_ + t) * (H_ * 4) +
                            (size_t)r * 4 + u];

                    float a0 = 0.f, a1 = 0.f, a2 = 0.f, a3 = 0.f;
                    int kk = hb + u;
                    int2 pk = hhpack[kk];
                    for (int i = 0; i < len; i += 8) {
                        kk += 8;
                        int2 pkn = hhpack[kk];   // next-window prefetch (slack-padded)
                        uint2 hw = *(const uint2*)((const char*)sh + ((size_t)pk.x << 3));
                        float v = __int_as_float(pk.y);
                        a0 += v * __uint_as_float(hw.x << 16);
                        a1 += v * __uint_as_float(hw.x & 0xffff0000u);
                        a2 += v * __uint_as_float(hw.y << 16);
                        a3 += v * __uint_as_float(hw.y & 0xffff0000u);
                        pk = pkn;
                    }
                    #pragma unroll
                    for (int off = 1; off <= 4; off <<= 1) {
                        a0 += __shfl_xor(a0, off);
                        a1 += __shfl_xor(a1, off);
                        a2 += __shfl_xor(a2, off);
                        a3 += __shfl_xor(a3, off);
                    }
                    if (u < 4) {
                        float acc = (u == 0) ? a0 : (u == 1) ? a1 : (u == 2) ? a2 : a3;
                        float pv = __uint_as_float((unsigned int)pus << 16);
                        float h = tanhf(acc + pv);
                        dst[(size_t)r * 4 + u] = f2bf(h);
                        int b = grp * 8 + hf * 4 + u;
                        out[(size_t)b * T_ * H_ + (size_t)t * H_ + r] = h;
                    }
                }
            }
        }

        // ---- per-XCD barrier: padded arrival slots + parallel lane polling ----
        __syncthreads();   // every wave drains vmcnt(0) before s_barrier -> h in L2
        {
            int target = t + 1;
            if (wave == 0) {
                if (lane == 0) {
                    asm volatile("s_waitcnt vmcnt(0)" ::: "memory");
                    __hip_atomic_store(myarr, target, __ATOMIC_RELAXED,
                                       __HIP_MEMORY_SCOPE_AGENT);
                }
                if (lane < nblk) {
                    while (__hip_atomic_load(&arrbase[lane * 16], __ATOMIC_RELAXED,
                                             __HIP_MEMORY_SCOPE_AGENT) < target) {
                        __builtin_amdgcn_s_sleep(1);
                    }
                }
            }
        }
        __syncthreads();
    }
}

// ---------------- host launch ----------------
extern "C" void kernel_launch(void* const* d_in, const int* in_sizes, int n_in,
                              void* d_out, int out_size, void* d_ws, size_t ws_size,
                              hipStream_t stream) {
    const float* x       = (const float*)d_in[0];
    const float* ih_vals = (const float*)d_in[1];
    const float* hh_vals = (const float*)d_in[2];
    const float* hh_bias = (const float*)d_in[3];
    const int*   ih_rows = (const int*)d_in[4];
    const int*   ih_cols = (const int*)d_in[5];
    const int*   hh_rows = (const int*)d_in[6];
    const int*   hh_cols = (const int*)d_in[7];
    float* out = (float*)d_out;

    const int nnz_ih = in_sizes[1];
    const int nnz_hh = in_sizes[2];

    char* ws = (char*)d_ws;
    size_t off = 0;
    auto alloc = [&](size_t bytes) -> void* {
        off = (off + 255) & ~(size_t)255;
        void* p = ws + off;
        off += bytes;
        return p;
    };

    unsigned short* xT2 = (unsigned short*)alloc((size_t)T_ * 8 * I_ * 8 * sizeof(unsigned short));
    int*   ih_rp  = (int*)alloc((H_ + 1) * sizeof(int));
    int*   hh_rp  = (int*)alloc((H_ + 1) * sizeof(int));
    int*   hh_pcnt = (int*)alloc(H_ * sizeof(int));

    const int ZINTS = 4 * H_ + 64 + 8 * 32 + 8 * 32 + 8 + 64 + 8 * 1024;
    int* zbase  = (int*)alloc((size_t)ZINTS * sizeof(int));
    int* ih_cnt = zbase;
    int* ih_cur = zbase + H_;
    int* hh_cnt = zbase + 2 * H_;
    int* hh_cur = zbase + 3 * H_;
    int* regcnt = zbase + 4 * H_;
    int* barcnt = regcnt + 64;
    int* bargen = barcnt + 8 * 32;
    int* owncnt = bargen + 8 * 32;
    int* owngrp = owncnt + 8;
    int* arrive = owngrp + 64;

    int2* ih_pack = (int2*)alloc((size_t)nnz_ih * sizeof(int2));
    size_t hh_pack_n = (size_t)2 * nnz_hh + 64;   // padded bound + prefetch slack
    int2* hh_pack = (int2*)alloc(hh_pack_n * sizeof(int2));
    unsigned short* hg = (unsigned short*)alloc((size_t)XCDS * 2 * 2 * H_ * 4 * sizeof(unsigned short)); // 1 MB
    unsigned short* pre = (unsigned short*)alloc((size_t)16 * T_ * H_ * 4 * sizeof(unsigned short)); // 67 MB

    hipMemsetAsync(zbase, 0, (size_t)ZINTS * sizeof(int), stream);
    hipMemsetAsync(hg, 0, (size_t)XCDS * 2 * 2 * H_ * 4 * sizeof(unsigned short), stream);
    hipMemsetAsync(hh_pack, 0, hh_pack_n * sizeof(int2), stream);

    transpose_x<<<dim3(I_ / 128, 8, T_), dim3(128, 8), 0, stream>>>(x, xT2);

    hist_rows<<<(nnz_ih + 255) / 256, 256, 0, stream>>>(ih_rows, nnz_ih, ih_cnt);
    scan_rows<<<1, 64, 0, stream>>>(ih_cnt, ih_rp, H_);
    scatter_pack<<<(nnz_ih + 255) / 256, 256, 0, stream>>>(ih_rows, ih_cols, ih_vals, nnz_ih,
                                                           ih_rp, ih_cur, ih_pack);
    hist_rows<<<(nnz_hh + 255) / 256, 256, 0, stream>>>(hh_rows, nnz_hh, hh_cnt);
    pad_counts<<<(H_ / 8 + 255) / 256, 256, 0, stream>>>(hh_cnt, hh_pcnt);
    scan_rows<<<1, 64, 0, stream>>>(hh_pcnt, hh_rp, H_);
    scatter_pack<<<(nnz_hh + 255) / 256, 256, 0, stream>>>(hh_rows, hh_cols, hh_vals, nnz_hh,
                                                           hh_rp, hh_cur, hh_pack);

    precompute_ih<<<dim3(H_ / 8 / 16, 8), dim3(1024), 0, stream>>>(xT2, ih_rp, ih_pack,
                                                                   hh_bias, pre);

    void* kargs[] = {
        (void*)&hh_rp, (void*)&hh_pack,
        (void*)&pre,
        (void*)&hg,
        (void*)&regcnt, (void*)&barcnt, (void*)&bargen,
        (void*)&owncnt, (void*)&owngrp,
        (void*)&arrive,
        (void*)&out,
    };
    hipLaunchCooperativeKernel((const void*)rnn_steps, dim3(RNN_BLOCKS), dim3(RNN_THREADS),
                               kargs, 0, stream);
}

// Round 15
// 1438.812 us; speedup vs baseline: 1.0233x; 1.0233x over previous
//
#include <hip/hip_runtime.h>
#include <hip/hip_cooperative_groups.h>
#include <math.h>

namespace cg = cooperative_groups;

#define B_ 64
#define T_ 128
#define I_ 1024
#define H_ 4096
#define XCDS 8

#define RNN_BLOCKS 256
#define RNN_THREADS 1024

#define MAXIT_IH 8    // 64 nnz/row registerized (Poisson(32)); tail fallback beyond

// ---------------- helpers ----------------
__device__ __forceinline__ unsigned short f2bf(float f) {
    unsigned int u = __float_as_uint(f);
    unsigned int r = (u + 0x7fffu + ((u >> 16) & 1u)) >> 16;
    return (unsigned short)r;
}

__device__ __forceinline__ void load2x16_sc0(const void* p0, const void* p1,
                                             uint4& a, uint4& b) {
    asm volatile(
        "global_load_dwordx4 %0, %2, off sc0\n\t"
        "global_load_dwordx4 %1, %3, off sc0\n\t"
        "s_waitcnt vmcnt(0)"
        : "=&v"(a), "=&v"(b)
        : "v"(p0), "v"(p1));
}

// ---------------- transpose x (B,T,I) -> xT2 (T, 8, I, 8) bf16 ----------------
__global__ void transpose_x(const float* __restrict__ x, unsigned short* __restrict__ xT2) {
    __shared__ float lds[8][129];
    int t  = blockIdx.z;
    int bg = blockIdx.y;
    int i0 = blockIdx.x * 128;
    int tx = threadIdx.x;   // 0..127
    int ty = threadIdx.y;   // 0..7
    int b = bg * 8 + ty;
    lds[ty][tx] = x[(size_t)b * T_ * I_ + (size_t)t * I_ + i0 + tx];
    __syncthreads();
    int n  = ty * 128 + tx;
    int ii = n >> 3;
    int bs = n & 7;
    xT2[(((size_t)t * 8 + bg) * I_ + i0 + ii) * 8 + bs] = f2bf(lds[bs][ii]);
}

// ---------------- CSR build ----------------
__global__ void hist_rows(const int* __restrict__ rows, int nnz, int* __restrict__ counts) {
    int k = blockIdx.x * blockDim.x + threadIdx.x;
    if (k < nnz) atomicAdd(&counts[rows[k]], 1);
}

// pad each group-of-8 rows to (group max rounded up to 8): uniform len, no guards
__global__ void pad_counts(const int* __restrict__ cnt, int* __restrict__ pcnt) {
    int grp = blockIdx.x * blockDim.x + threadIdx.x;
    if (grp >= H_ / 8) return;
    int m = 0;
    #pragma unroll
    for (int j = 0; j < 8; ++j) m = max(m, cnt[grp * 8 + j]);
    m = (m + 7) & ~7;
    #pragma unroll
    for (int j = 0; j < 8; ++j) pcnt[grp * 8 + j] = m;
}

__global__ void scan_rows(const int* __restrict__ counts, int* __restrict__ rp, int n) {
    int lane = threadIdx.x;      // 0..63
    int chunk = n / 64;
    int base = lane * chunk;
    int s = 0;
    for (int j = 0; j < chunk; ++j) s += counts[base + j];
    int pre = s;
    for (int off = 1; off < 64; off <<= 1) {
        int up = __shfl_up(pre, off, 64);
        if (lane >= off) pre += up;
    }
    int run = pre - s;
    for (int j = 0; j < chunk; ++j) { rp[base + j] = run; run += counts[base + j]; }
    if (lane == 63) rp[n] = run;
}

__global__ void scatter_pack(const int* __restrict__ rows, const int* __restrict__ cols,
                             const float* __restrict__ vals, int nnz,
                             const int* __restrict__ rp, int* __restrict__ cursor,
                             int2* __restrict__ pack) {
    int k = blockIdx.x * blockDim.x + threadIdx.x;
    if (k < nnz) {
        int r = rows[k];
        int pos = atomicAdd(&cursor[r], 1);
        pack[rp[r] + pos] = make_int2(cols[k], __float_as_int(vals[k]));
    }
}

// ---------------- kernel P: pre[t] = W_ih * x_t + bias  (bf16 out) ----------------
// r12 proven form: bf16 x, 16 waves share double-buffered staging,
// issue-early/write-late, one barrier/step, CSR slice registerized.
__global__ __launch_bounds__(1024)
void precompute_ih(const unsigned short* __restrict__ xT2,
                   const int* __restrict__ rp, const int2* __restrict__ pack,
                   const float* __restrict__ bias,
                   unsigned short* __restrict__ pre) {
    __shared__ __align__(16) unsigned short xs[2][I_ * 8];   // 2 x 16 KB double buffer
    int grp  = blockIdx.y;
    int wave = threadIdx.x >> 6;                  // 0..15
    int lane = threadIdx.x & 63;
    int rs = lane >> 3;   // row within group
    int u  = lane & 7;    // position within window

    int g = blockIdx.x * 16 + wave;               // 0..511
    int r = g * 8 + rs;
    int hb = rp[r];
    int len = rp[r + 1] - hb;
    int lm = len;
    lm = max(lm, __shfl_xor(lm, 8));
    lm = max(lm, __shfl_xor(lm, 16));
    lm = max(lm, __shfl_xor(lm, 32));
    int lmax = __builtin_amdgcn_readfirstlane(lm);
    float bsv = bias[r];

    // registerize the CSR slice (t-invariant): byte offsets pre-shifted
    int   pcol[MAXIT_IH];
    float pval[MAXIT_IH];
    #pragma unroll
    for (int it = 0; it < MAXIT_IH; ++it) {
        int2 pk = make_int2(0, 0);
        if (it * 8 + u < len) pk = pack[hb + it * 8 + u];
        pcol[it] = pk.x << 4;                 // col * 8 bf16 * 2 B
        pval[it] = __int_as_float(pk.y);
    }

    // prologue: stage t=0 into buffer 0
    {
        const uint4* s = (const uint4*)(xT2 + ((size_t)0 * 8 + grp) * (I_ * 8));
        ((uint4*)xs[0])[threadIdx.x] = s[threadIdx.x];   // 1024 x 16 B = 16 KB
    }
    __syncthreads();

    for (int t = 0; t < T_; ++t) {
        int cur = t & 1;

        // issue next step's staging load early (latency hides under compute)
        uint4 st0;
        bool havenext = (t + 1 < T_);
        if (havenext) {
            const uint4* s = (const uint4*)(xT2 + ((size_t)(t + 1) * 8 + grp) * (I_ * 8));
            st0 = s[threadIdx.x];
        }

        const char* xb = (const char*)xs[cur];
        float a[8];
        #pragma unroll
        for (int j = 0; j < 8; ++j) a[j] = 0.0f;

        // branchless registerized windows (padded lanes read col 0, add +0.0)
        #pragma unroll
        for (int it = 0; it < MAXIT_IH; ++it) {
            uint4 xw = *(const uint4*)(xb + pcol[it]);
            float v = pval[it];
            a[0] += v * __uint_as_float(xw.x << 16);
            a[1] += v * __uint_as_float(xw.x & 0xffff0000u);
            a[2] += v * __uint_as_float(xw.y << 16);
            a[3] += v * __uint_as_float(xw.y & 0xffff0000u);
            a[4] += v * __uint_as_float(xw.z << 16);
            a[5] += v * __uint_as_float(xw.z & 0xffff0000u);
            a[6] += v * __uint_as_float(xw.w << 16);
            a[7] += v * __uint_as_float(xw.w & 0xffff0000u);
        }
        if (lmax > 8 * MAXIT_IH) {   // rare tail, same summation order
            int kk = hb + 8 * MAXIT_IH + u;
            for (int i = 8 * MAXIT_IH; i < lmax; i += 8, kk += 8) {
                int2 pk = make_int2(0, 0);
                if (i + u < len) pk = pack[kk];
                uint4 xw = *(const uint4*)(xb + ((size_t)pk.x << 4));
                float v = __int_as_float(pk.y);
                a[0] += v * __uint_as_float(xw.x << 16);
                a[1] += v * __uint_as_float(xw.x & 0xffff0000u);
                a[2] += v * __uint_as_float(xw.y << 16);
                a[3] += v * __uint_as_float(xw.y & 0xffff0000u);
                a[4] += v * __uint_as_float(xw.z << 16);
                a[5] += v * __uint_as_float(xw.z & 0xffff0000u);
                a[6] += v * __uint_as_float(xw.w << 16);
                a[7] += v * __uint_as_float(xw.w & 0xffff0000u);
            }
        }
        #pragma unroll
        for (int off = 1; off <= 4; off <<= 1) {
            #pragma unroll
            for (int j = 0; j < 8; ++j) a[j] += __shfl_xor(a[j], off);
        }
        float sel = (u == 0) ? a[0] : (u == 1) ? a[1] : (u == 2) ? a[2] : (u == 3) ? a[3]
                  : (u == 4) ? a[4] : (u == 5) ? a[5] : (u == 6) ? a[6] : a[7];
        float p = sel + bsv;
        int hf = u >> 2, cc = u & 3;
        pre[((size_t)(grp * 2 + hf) * T_ + t) * (H_ * 4) + (size_t)r * 4 + cc] = f2bf(p);

        // write-late: commit next step's staging to the other buffer
        if (havenext) {
            ((uint4*)xs[cur ^ 1])[threadIdx.x] = st0;
        }
        __syncthreads();   // xs[cur^1] published; readers of xs[cur] done
    }
}

// ---------------- kernel R: persistent XCD-local recurrence ----------------
// r12 structure (bf16 state, padded guard-free CSR, 1-deep hhpack prefetch,
// early pre load) with r12's PROVEN central-counter barrier protocol, scoped
// to (xcd, half) groups of 16 blocks: the two batch-halves share no data
// (hf blocks read/write only h[.][hf]), so each half syncs independently —
// half rendezvous width, halves may pipeline-slip.
// hg layout: hg[((grp*2 + parity)*2 + half) * (H_*4)]  (ushort elements)
__global__ __launch_bounds__(RNN_THREADS, 1)
void rnn_steps(const int* __restrict__ hhp, const int2* __restrict__ hhpack,
               const unsigned short* __restrict__ pre,
               unsigned short* __restrict__ hg,
               int* __restrict__ regcnt, int* __restrict__ barcnt, int* __restrict__ bargen,
               int* __restrict__ owncnt, int* __restrict__ owngrp,
               float* __restrict__ out) {
    cg::grid_group grid = cg::this_grid();
    __shared__ __align__(16) unsigned short sh[H_ * 4];   // 32 KB: bf16 h_prev
    __shared__ int meta[2];

    int tid = threadIdx.x;
    if (tid == 0) {
        int x;
        asm volatile("s_getreg_b32 %0, hwreg(HW_REG_XCC_ID)" : "=s"(x));
        x &= 7;
        int slot = __hip_atomic_fetch_add(&regcnt[x], 1, __ATOMIC_RELAXED,
                                          __HIP_MEMORY_SCOPE_AGENT);
        meta[0] = x;
        meta[1] = slot;
    }
    __syncthreads();
    int xcd  = meta[0];
    int slot = meta[1];
    grid.sync();

    if (blockIdx.x == 0 && tid == 0) {
        int list[XCDS]; int nz = 0;
        for (int j = 0; j < XCDS; ++j) {
            owncnt[j] = 0;
            if (__hip_atomic_load(&regcnt[j], __ATOMIC_RELAXED,
                                  __HIP_MEMORY_SCOPE_AGENT) > 0) list[nz++] = j;
        }
        int rr = 0;
        for (int j = 0; j < XCDS; ++j) {
            int present = __hip_atomic_load(&regcnt[j], __ATOMIC_RELAXED,
                                            __HIP_MEMORY_SCOPE_AGENT) > 0;
            int owner = present ? j : list[rr++ % nz];
            owngrp[owner * 8 + owncnt[owner]] = j;
            owncnt[owner] += 1;
        }
    }
    grid.sync();

    int nblk = __hip_atomic_load(&regcnt[xcd], __ATOMIC_RELAXED, __HIP_MEMORY_SCOPE_AGENT);
    int nown = owncnt[xcd];

    int wave = tid >> 6;
    int lane = tid & 63;
    int rs   = lane >> 3;
    int u    = lane & 7;

    // half assignment (robust to nblk==1)
    int hfbeg, hfend, mywave, nwh, myhf, hcnt;
    if (nblk >= 2) {
        int hf = slot & 1;
        hfbeg = hf; hfend = hf + 1;
        int nhb = (hf == 0) ? ((nblk + 1) >> 1) : (nblk >> 1);
        mywave = (slot >> 1) * (RNN_THREADS / 64) + wave;
        nwh = nhb * (RNN_THREADS / 64);
        myhf = hf; hcnt = nhb;
    } else {
        hfbeg = 0; hfend = 2;
        mywave = wave; nwh = RNN_THREADS / 64;
        myhf = 0; hcnt = 1;
    }

    // per-(xcd, half) barrier state: 8-int (32 B) apart within the xcd's row
    int* bc   = &barcnt[xcd * 32 + myhf * 8];
    int* bgen = &bargen[xcd * 32 + myhf * 8];

    for (int t = 0; t < T_; ++t) {
        for (int oi = 0; oi < nown; ++oi) {
            int grp = owngrp[xcd * 8 + oi];
            for (int hf = hfbeg; hf < hfend; ++hf) {
                const unsigned short* src =
                    hg + (size_t)((grp * 2 + (t & 1)) * 2 + hf) * (H_ * 4);
                unsigned short* dst =
                    hg + (size_t)((grp * 2 + ((t + 1) & 1)) * 2 + hf) * (H_ * 4);

                // ---- fill sh with bf16 h_prev (sc0: bypass stale L1, hit L2) ----
                __syncthreads();   // prior readers of sh are done
                {
                    uint4 v0, v1;
                    const char* s = (const char*)src;
                    load2x16_sc0(s + (size_t)tid * 16,
                                 s + (size_t)(1024 + tid) * 16, v0, v1);
                    uint4* s4 = (uint4*)sh;
                    s4[tid]        = v0;
                    s4[1024 + tid] = v1;
                }
                __syncthreads();   // sh ready

                // ---- compute: hh SpMM rows + pre + tanh (guard-free padded CSR) ----
                for (int g = mywave; g < H_ / 8; g += nwh) {
                    int r  = g * 8 + rs;
                    int hb = hhp[r];
                    int len = hhp[r + 1] - hb;   // padded: uniform across group

                    // early pre load (u<8 index safe; consumed after reduce)
                    unsigned short pus =
                        pre[((size_t)(grp * 2 + hf) * T_ + t) * (H_ * 4) +
                            (size_t)r * 4 + u];

                    float a0 = 0.f, a1 = 0.f, a2 = 0.f, a3 = 0.f;
                    int kk = hb + u;
                    int2 pk = hhpack[kk];
                    for (int i = 0; i < len; i += 8) {
                        kk += 8;
                        int2 pkn = hhpack[kk];   // next-window prefetch (slack-padded)
                        uint2 hw = *(const uint2*)((const char*)sh + ((size_t)pk.x << 3));
                        float v = __int_as_float(pk.y);
                        a0 += v * __uint_as_float(hw.x << 16);
                        a1 += v * __uint_as_float(hw.x & 0xffff0000u);
                        a2 += v * __uint_as_float(hw.y << 16);
                        a3 += v * __uint_as_float(hw.y & 0xffff0000u);
                        pk = pkn;
                    }
                    #pragma unroll
                    for (int off = 1; off <= 4; off <<= 1) {
                        a0 += __shfl_xor(a0, off);
                        a1 += __shfl_xor(a1, off);
                        a2 += __shfl_xor(a2, off);
                        a3 += __shfl_xor(a3, off);
                    }
                    if (u < 4) {
                        float acc = (u == 0) ? a0 : (u == 1) ? a1 : (u == 2) ? a2 : a3;
                        float pv = __uint_as_float((unsigned int)pus << 16);
                        float h = tanhf(acc + pv);
                        dst[(size_t)r * 4 + u] = f2bf(h);
                        int b = grp * 8 + hf * 4 + u;
                        out[(size_t)b * T_ * H_ + (size_t)t * H_ + r] = h;
                    }
                }
            }
        }

        // ---- per-(xcd, half) barrier (r12's proven protocol, narrower group) ----
        __syncthreads();   // drains this block's h stores to L2 (vmcnt(0) before s_barrier)
        if (tid == 0) {
            asm volatile("s_waitcnt vmcnt(0)" ::: "memory");
            int target = t + 1;
            int old = __hip_atomic_fetch_add(bc, 1, __ATOMIC_RELAXED,
                                             __HIP_MEMORY_SCOPE_AGENT);
            if (old == hcnt - 1) {
                __hip_atomic_store(bc, 0, __ATOMIC_RELAXED, __HIP_MEMORY_SCOPE_AGENT);
                __hip_atomic_store(bgen, target, __ATOMIC_RELAXED, __HIP_MEMORY_SCOPE_AGENT);
            } else {
                while (__hip_atomic_load(bgen, __ATOMIC_RELAXED,
                                         __HIP_MEMORY_SCOPE_AGENT) < target) {
                    __builtin_amdgcn_s_sleep(1);
                }
            }
        }
        __syncthreads();
    }
}

// ---------------- host launch ----------------
extern "C" void kernel_launch(void* const* d_in, const int* in_sizes, int n_in,
                              void* d_out, int out_size, void* d_ws, size_t ws_size,
                              hipStream_t stream) {
    const float* x       = (const float*)d_in[0];
    const float* ih_vals = (const float*)d_in[1];
    const float* hh_vals = (const float*)d_in[2];
    const float* hh_bias = (const float*)d_in[3];
    const int*   ih_rows = (const int*)d_in[4];
    const int*   ih_cols = (const int*)d_in[5];
    const int*   hh_rows = (const int*)d_in[6];
    const int*   hh_cols = (const int*)d_in[7];
    float* out = (float*)d_out;

    const int nnz_ih = in_sizes[1];
    const int nnz_hh = in_sizes[2];

    char* ws = (char*)d_ws;
    size_t off = 0;
    auto alloc = [&](size_t bytes) -> void* {
        off = (off + 255) & ~(size_t)255;
        void* p = ws + off;
        off += bytes;
        return p;
    };

    unsigned short* xT2 = (unsigned short*)alloc((size_t)T_ * 8 * I_ * 8 * sizeof(unsigned short));
    int*   ih_rp  = (int*)alloc((H_ + 1) * sizeof(int));
    int*   hh_rp  = (int*)alloc((H_ + 1) * sizeof(int));
    int*   hh_pcnt = (int*)alloc(H_ * sizeof(int));

    const int ZINTS = 4 * H_ + 64 + 8 * 32 + 8 * 32 + 8 + 64;
    int* zbase  = (int*)alloc((size_t)ZINTS * sizeof(int));
    int* ih_cnt = zbase;
    int* ih_cur = zbase + H_;
    int* hh_cnt = zbase + 2 * H_;
    int* hh_cur = zbase + 3 * H_;
    int* regcnt = zbase + 4 * H_;
    int* barcnt = regcnt + 64;
    int* bargen = barcnt + 8 * 32;
    int* owncnt = bargen + 8 * 32;
    int* owngrp = owncnt + 8;

    int2* ih_pack = (int2*)alloc((size_t)nnz_ih * sizeof(int2));
    size_t hh_pack_n = (size_t)2 * nnz_hh + 64;   // padded bound + prefetch slack
    int2* hh_pack = (int2*)alloc(hh_pack_n * sizeof(int2));
    unsigned short* hg = (unsigned short*)alloc((size_t)XCDS * 2 * 2 * H_ * 4 * sizeof(unsigned short)); // 1 MB
    unsigned short* pre = (unsigned short*)alloc((size_t)16 * T_ * H_ * 4 * sizeof(unsigned short)); // 67 MB

    hipMemsetAsync(zbase, 0, (size_t)ZINTS * sizeof(int), stream);
    hipMemsetAsync(hg, 0, (size_t)XCDS * 2 * 2 * H_ * 4 * sizeof(unsigned short), stream);
    hipMemsetAsync(hh_pack, 0, hh_pack_n * sizeof(int2), stream);

    transpose_x<<<dim3(I_ / 128, 8, T_), dim3(128, 8), 0, stream>>>(x, xT2);

    hist_rows<<<(nnz_ih + 255) / 256, 256, 0, stream>>>(ih_rows, nnz_ih, ih_cnt);
    scan_rows<<<1, 64, 0, stream>>>(ih_cnt, ih_rp, H_);
    scatter_pack<<<(nnz_ih + 255) / 256, 256, 0, stream>>>(ih_rows, ih_cols, ih_vals, nnz_ih,
                                                           ih_rp, ih_cur, ih_pack);
    hist_rows<<<(nnz_hh + 255) / 256, 256, 0, stream>>>(hh_rows, nnz_hh, hh_cnt);
    pad_counts<<<(H_ / 8 + 255) / 256, 256, 0, stream>>>(hh_cnt, hh_pcnt);
    scan_rows<<<1, 64, 0, stream>>>(hh_pcnt, hh_rp, H_);
    scatter_pack<<<(nnz_hh + 255) / 256, 256, 0, stream>>>(hh_rows, hh_cols, hh_vals, nnz_hh,
                                                           hh_rp, hh_cur, hh_pack);

    precompute_ih<<<dim3(H_ / 8 / 16, 8), dim3(1024), 0, stream>>>(xT2, ih_rp, ih_pack,
                                                                   hh_bias, pre);

    void* kargs[] = {
        (void*)&hh_rp, (void*)&hh_pack,
        (void*)&pre,
        (void*)&hg,
        (void*)&regcnt, (void*)&barcnt, (void*)&bargen,
        (void*)&owncnt, (void*)&owngrp,
        (void*)&out,
    };
    hipLaunchCooperativeKernel((const void*)rnn_steps, dim3(RNN_BLOCKS), dim3(RNN_THREADS),
                               kargs, 0, stream);
}

// Round 16
// 1419.570 us; speedup vs baseline: 1.0372x; 1.0136x over previous
//
#include <hip/hip_runtime.h>
#include <hip/hip_cooperative_groups.h>
#include <math.h>

namespace cg = cooperative_groups;

#define B_ 64
#define T_ 128
#define I_ 1024
#define H_ 4096
#define XCDS 8

#define RNN_BLOCKS 256
#define RNN_THREADS 1024

#define MAXIT_IH 8    // 64 nnz/row registerized (Poisson(32)); tail fallback beyond

// ---------------- helpers ----------------
__device__ __forceinline__ unsigned short f2bf(float f) {
    unsigned int u = __float_as_uint(f);
    unsigned int r = (u + 0x7fffu + ((u >> 16) & 1u)) >> 16;
    return (unsigned short)r;
}

__device__ __forceinline__ void load2x16_sc0(const void* p0, const void* p1,
                                             uint4& a, uint4& b) {
    asm volatile(
        "global_load_dwordx4 %0, %2, off sc0\n\t"
        "global_load_dwordx4 %1, %3, off sc0\n\t"
        "s_waitcnt vmcnt(0)"
        : "=&v"(a), "=&v"(b)
        : "v"(p0), "v"(p1));
}

// ---------------- transpose x (B,T,I) -> xT2 (T, 8, I, 8) bf16 ----------------
__global__ void transpose_x(const float* __restrict__ x, unsigned short* __restrict__ xT2) {
    __shared__ float lds[8][129];
    int t  = blockIdx.z;
    int bg = blockIdx.y;
    int i0 = blockIdx.x * 128;
    int tx = threadIdx.x;   // 0..127
    int ty = threadIdx.y;   // 0..7
    int b = bg * 8 + ty;
    lds[ty][tx] = x[(size_t)b * T_ * I_ + (size_t)t * I_ + i0 + tx];
    __syncthreads();
    int n  = ty * 128 + tx;
    int ii = n >> 3;
    int bs = n & 7;
    xT2[(((size_t)t * 8 + bg) * I_ + i0 + ii) * 8 + bs] = f2bf(lds[bs][ii]);
}

// ---------------- CSR build ----------------
__global__ void hist_rows(const int* __restrict__ rows, int nnz, int* __restrict__ counts) {
    int k = blockIdx.x * blockDim.x + threadIdx.x;
    if (k < nnz) atomicAdd(&counts[rows[k]], 1);
}

// pad each group-of-8 rows to (group max rounded up to 8): uniform len, no guards
__global__ void pad_counts(const int* __restrict__ cnt, int* __restrict__ pcnt) {
    int grp = blockIdx.x * blockDim.x + threadIdx.x;
    if (grp >= H_ / 8) return;
    int m = 0;
    #pragma unroll
    for (int j = 0; j < 8; ++j) m = max(m, cnt[grp * 8 + j]);
    m = (m + 7) & ~7;
    #pragma unroll
    for (int j = 0; j < 8; ++j) pcnt[grp * 8 + j] = m;
}

__global__ void scan_rows(const int* __restrict__ counts, int* __restrict__ rp, int n) {
    int lane = threadIdx.x;      // 0..63
    int chunk = n / 64;
    int base = lane * chunk;
    int s = 0;
    for (int j = 0; j < chunk; ++j) s += counts[base + j];
    int pre = s;
    for (int off = 1; off < 64; off <<= 1) {
        int up = __shfl_up(pre, off, 64);
        if (lane >= off) pre += up;
    }
    int run = pre - s;
    for (int j = 0; j < chunk; ++j) { rp[base + j] = run; run += counts[base + j]; }
    if (lane == 63) rp[n] = run;
}

__global__ void scatter_pack(const int* __restrict__ rows, const int* __restrict__ cols,
                             const float* __restrict__ vals, int nnz,
                             const int* __restrict__ rp, int* __restrict__ cursor,
                             int2* __restrict__ pack) {
    int k = blockIdx.x * blockDim.x + threadIdx.x;
    if (k < nnz) {
        int r = rows[k];
        int pos = atomicAdd(&cursor[r], 1);
        pack[rp[r] + pos] = make_int2(cols[k], __float_as_int(vals[k]));
    }
}

// hh pack compressed to 4 B/nnz: (bf16(val) << 16) | col.  2.6 MB padded ->
// L2-resident per XCD (was 5.2 MB > 4 MB L2).  val bits usable as f32 by AND.
__global__ void scatter_pack_bf16(const int* __restrict__ rows, const int* __restrict__ cols,
                                  const float* __restrict__ vals, int nnz,
                                  const int* __restrict__ rp, int* __restrict__ cursor,
                                  unsigned int* __restrict__ pack) {
    int k = blockIdx.x * blockDim.x + threadIdx.x;
    if (k < nnz) {
        int r = rows[k];
        int pos = atomicAdd(&cursor[r], 1);
        pack[rp[r] + pos] = ((unsigned int)f2bf(vals[k]) << 16) | (unsigned int)cols[k];
    }
}

// ---------------- kernel P: pre[t] = W_ih * x_t + bias  (bf16 out) ----------------
// r12 proven form: bf16 x, 16 waves share double-buffered staging,
// issue-early/write-late, one barrier/step, CSR slice registerized.
__global__ __launch_bounds__(1024)
void precompute_ih(const unsigned short* __restrict__ xT2,
                   const int* __restrict__ rp, const int2* __restrict__ pack,
                   const float* __restrict__ bias,
                   unsigned short* __restrict__ pre) {
    __shared__ __align__(16) unsigned short xs[2][I_ * 8];   // 2 x 16 KB double buffer
    int grp  = blockIdx.y;
    int wave = threadIdx.x >> 6;                  // 0..15
    int lane = threadIdx.x & 63;
    int rs = lane >> 3;   // row within group
    int u  = lane & 7;    // position within window

    int g = blockIdx.x * 16 + wave;               // 0..511
    int r = g * 8 + rs;
    int hb = rp[r];
    int len = rp[r + 1] - hb;
    int lm = len;
    lm = max(lm, __shfl_xor(lm, 8));
    lm = max(lm, __shfl_xor(lm, 16));
    lm = max(lm, __shfl_xor(lm, 32));
    int lmax = __builtin_amdgcn_readfirstlane(lm);
    float bsv = bias[r];

    // registerize the CSR slice (t-invariant): byte offsets pre-shifted
    int   pcol[MAXIT_IH];
    float pval[MAXIT_IH];
    #pragma unroll
    for (int it = 0; it < MAXIT_IH; ++it) {
        int2 pk = make_int2(0, 0);
        if (it * 8 + u < len) pk = pack[hb + it * 8 + u];
        pcol[it] = pk.x << 4;                 // col * 8 bf16 * 2 B
        pval[it] = __int_as_float(pk.y);
    }

    // prologue: stage t=0 into buffer 0
    {
        const uint4* s = (const uint4*)(xT2 + ((size_t)0 * 8 + grp) * (I_ * 8));
        ((uint4*)xs[0])[threadIdx.x] = s[threadIdx.x];   // 1024 x 16 B = 16 KB
    }
    __syncthreads();

    for (int t = 0; t < T_; ++t) {
        int cur = t & 1;

        // issue next step's staging load early (latency hides under compute)
        uint4 st0;
        bool havenext = (t + 1 < T_);
        if (havenext) {
            const uint4* s = (const uint4*)(xT2 + ((size_t)(t + 1) * 8 + grp) * (I_ * 8));
            st0 = s[threadIdx.x];
        }

        const char* xb = (const char*)xs[cur];
        float a[8];
        #pragma unroll
        for (int j = 0; j < 8; ++j) a[j] = 0.0f;

        // branchless registerized windows (padded lanes read col 0, add +0.0)
        #pragma unroll
        for (int it = 0; it < MAXIT_IH; ++it) {
            uint4 xw = *(const uint4*)(xb + pcol[it]);
            float v = pval[it];
            a[0] += v * __uint_as_float(xw.x << 16);
            a[1] += v * __uint_as_float(xw.x & 0xffff0000u);
            a[2] += v * __uint_as_float(xw.y << 16);
            a[3] += v * __uint_as_float(xw.y & 0xffff0000u);
            a[4] += v * __uint_as_float(xw.z << 16);
            a[5] += v * __uint_as_float(xw.z & 0xffff0000u);
            a[6] += v * __uint_as_float(xw.w << 16);
            a[7] += v * __uint_as_float(xw.w & 0xffff0000u);
        }
        if (lmax > 8 * MAXIT_IH) {   // rare tail, same summation order
            int kk = hb + 8 * MAXIT_IH + u;
            for (int i = 8 * MAXIT_IH; i < lmax; i += 8, kk += 8) {
                int2 pk = make_int2(0, 0);
                if (i + u < len) pk = pack[kk];
                uint4 xw = *(const uint4*)(xb + ((size_t)pk.x << 4));
                float v = __int_as_float(pk.y);
                a[0] += v * __uint_as_float(xw.x << 16);
                a[1] += v * __uint_as_float(xw.x & 0xffff0000u);
                a[2] += v * __uint_as_float(xw.y << 16);
                a[3] += v * __uint_as_float(xw.y & 0xffff0000u);
                a[4] += v * __uint_as_float(xw.z << 16);
                a[5] += v * __uint_as_float(xw.z & 0xffff0000u);
                a[6] += v * __uint_as_float(xw.w << 16);
                a[7] += v * __uint_as_float(xw.w & 0xffff0000u);
            }
        }
        #pragma unroll
        for (int off = 1; off <= 4; off <<= 1) {
            #pragma unroll
            for (int j = 0; j < 8; ++j) a[j] += __shfl_xor(a[j], off);
        }
        float sel = (u == 0) ? a[0] : (u == 1) ? a[1] : (u == 2) ? a[2] : (u == 3) ? a[3]
                  : (u == 4) ? a[4] : (u == 5) ? a[5] : (u == 6) ? a[6] : a[7];
        float p = sel + bsv;
        int hf = u >> 2, cc = u & 3;
        pre[((size_t)(grp * 2 + hf) * T_ + t) * (H_ * 4) + (size_t)r * 4 + cc] = f2bf(p);

        // write-late: commit next step's staging to the other buffer
        if (havenext) {
            ((uint4*)xs[cur ^ 1])[threadIdx.x] = st0;
        }
        __syncthreads();   // xs[cur^1] published; readers of xs[cur] done
    }
}

// ---------------- kernel R: persistent XCD-local recurrence ----------------
// r15 structure (bf16 state, padded guard-free CSR, 1-deep prefetch, early pre
// load, per-(xcd,half) central-counter barrier). ONLY delta: hhpack is 4 B/nnz
// ((bf16val<<16)|col) -> 2.6 MB padded, L2-resident; unpack = 2 VALU ops.
// hg layout: hg[((grp*2 + parity)*2 + half) * (H_*4)]  (ushort elements)
__global__ __launch_bounds__(RNN_THREADS, 1)
void rnn_steps(const int* __restrict__ hhp, const unsigned int* __restrict__ hhpack,
               const unsigned short* __restrict__ pre,
               unsigned short* __restrict__ hg,
               int* __restrict__ regcnt, int* __restrict__ barcnt, int* __restrict__ bargen,
               int* __restrict__ owncnt, int* __restrict__ owngrp,
               float* __restrict__ out) {
    cg::grid_group grid = cg::this_grid();
    __shared__ __align__(16) unsigned short sh[H_ * 4];   // 32 KB: bf16 h_prev
    __shared__ int meta[2];

    int tid = threadIdx.x;
    if (tid == 0) {
        int x;
        asm volatile("s_getreg_b32 %0, hwreg(HW_REG_XCC_ID)" : "=s"(x));
        x &= 7;
        int slot = __hip_atomic_fetch_add(&regcnt[x], 1, __ATOMIC_RELAXED,
                                          __HIP_MEMORY_SCOPE_AGENT);
        meta[0] = x;
        meta[1] = slot;
    }
    __syncthreads();
    int xcd  = meta[0];
    int slot = meta[1];
    grid.sync();

    if (blockIdx.x == 0 && tid == 0) {
        int list[XCDS]; int nz = 0;
        for (int j = 0; j < XCDS; ++j) {
            owncnt[j] = 0;
            if (__hip_atomic_load(&regcnt[j], __ATOMIC_RELAXED,
                                  __HIP_MEMORY_SCOPE_AGENT) > 0) list[nz++] = j;
        }
        int rr = 0;
        for (int j = 0; j < XCDS; ++j) {
            int present = __hip_atomic_load(&regcnt[j], __ATOMIC_RELAXED,
                                            __HIP_MEMORY_SCOPE_AGENT) > 0;
            int owner = present ? j : list[rr++ % nz];
            owngrp[owner * 8 + owncnt[owner]] = j;
            owncnt[owner] += 1;
        }
    }
    grid.sync();

    int nblk = __hip_atomic_load(&regcnt[xcd], __ATOMIC_RELAXED, __HIP_MEMORY_SCOPE_AGENT);
    int nown = owncnt[xcd];

    int wave = tid >> 6;
    int lane = tid & 63;
    int rs   = lane >> 3;
    int u    = lane & 7;

    // half assignment (robust to nblk==1)
    int hfbeg, hfend, mywave, nwh, myhf, hcnt;
    if (nblk >= 2) {
        int hf = slot & 1;
        hfbeg = hf; hfend = hf + 1;
        int nhb = (hf == 0) ? ((nblk + 1) >> 1) : (nblk >> 1);
        mywave = (slot >> 1) * (RNN_THREADS / 64) + wave;
        nwh = nhb * (RNN_THREADS / 64);
        myhf = hf; hcnt = nhb;
    } else {
        hfbeg = 0; hfend = 2;
        mywave = wave; nwh = RNN_THREADS / 64;
        myhf = 0; hcnt = 1;
    }

    // per-(xcd, half) barrier state: 8-int (32 B) apart within the xcd's row
    int* bc   = &barcnt[xcd * 32 + myhf * 8];
    int* bgen = &bargen[xcd * 32 + myhf * 8];

    for (int t = 0; t < T_; ++t) {
        for (int oi = 0; oi < nown; ++oi) {
            int grp = owngrp[xcd * 8 + oi];
            for (int hf = hfbeg; hf < hfend; ++hf) {
                const unsigned short* src =
                    hg + (size_t)((grp * 2 + (t & 1)) * 2 + hf) * (H_ * 4);
                unsigned short* dst =
                    hg + (size_t)((grp * 2 + ((t + 1) & 1)) * 2 + hf) * (H_ * 4);

                // ---- fill sh with bf16 h_prev (sc0: bypass stale L1, hit L2) ----
                __syncthreads();   // prior readers of sh are done
                {
                    uint4 v0, v1;
                    const char* s = (const char*)src;
                    load2x16_sc0(s + (size_t)tid * 16,
                                 s + (size_t)(1024 + tid) * 16, v0, v1);
                    uint4* s4 = (uint4*)sh;
                    s4[tid]        = v0;
                    s4[1024 + tid] = v1;
                }
                __syncthreads();   // sh ready

                // ---- compute: hh SpMM rows + pre + tanh (guard-free padded CSR) ----
                for (int g = mywave; g < H_ / 8; g += nwh) {
                    int r  = g * 8 + rs;
                    int hb = hhp[r];
                    int len = hhp[r + 1] - hb;   // padded: uniform across group

                    // early pre load (u<8 index safe; consumed after reduce)
                    unsigned short pus =
                        pre[((size_t)(grp * 2 + hf) * T_ + t) * (H_ * 4) +
                            (size_t)r * 4 + u];

                    float a0 = 0.f, a1 = 0.f, a2 = 0.f, a3 = 0.f;
                    int kk = hb + u;
                    unsigned int pk = hhpack[kk];
                    for (int i = 0; i < len; i += 8) {
                        kk += 8;
                        unsigned int pkn = hhpack[kk];   // next-window prefetch (slack-padded)
                        uint2 hw = *(const uint2*)((const char*)sh +
                                                   ((size_t)(pk & 0xffffu) << 3));
                        float v = __uint_as_float(pk & 0xffff0000u);
                        a0 += v * __uint_as_float(hw.x << 16);
                        a1 += v * __uint_as_float(hw.x & 0xffff0000u);
                        a2 += v * __uint_as_float(hw.y << 16);
                        a3 += v * __uint_as_float(hw.y & 0xffff0000u);
                        pk = pkn;
                    }
                    #pragma unroll
                    for (int off = 1; off <= 4; off <<= 1) {
                        a0 += __shfl_xor(a0, off);
                        a1 += __shfl_xor(a1, off);
                        a2 += __shfl_xor(a2, off);
                        a3 += __shfl_xor(a3, off);
                    }
                    if (u < 4) {
                        float acc = (u == 0) ? a0 : (u == 1) ? a1 : (u == 2) ? a2 : a3;
                        float pv = __uint_as_float((unsigned int)pus << 16);
                        float h = tanhf(acc + pv);
                        dst[(size_t)r * 4 + u] = f2bf(h);
                        int b = grp * 8 + hf * 4 + u;
                        out[(size_t)b * T_ * H_ + (size_t)t * H_ + r] = h;
                    }
                }
            }
        }

        // ---- per-(xcd, half) barrier (r12's proven protocol, narrower group) ----
        __syncthreads();   // drains this block's h stores to L2 (vmcnt(0) before s_barrier)
        if (tid == 0) {
            asm volatile("s_waitcnt vmcnt(0)" ::: "memory");
            int target = t + 1;
            int old = __hip_atomic_fetch_add(bc, 1, __ATOMIC_RELAXED,
                                             __HIP_MEMORY_SCOPE_AGENT);
            if (old == hcnt - 1) {
                __hip_atomic_store(bc, 0, __ATOMIC_RELAXED, __HIP_MEMORY_SCOPE_AGENT);
                __hip_atomic_store(bgen, target, __ATOMIC_RELAXED, __HIP_MEMORY_SCOPE_AGENT);
            } else {
                while (__hip_atomic_load(bgen, __ATOMIC_RELAXED,
                                         __HIP_MEMORY_SCOPE_AGENT) < target) {
                    __builtin_amdgcn_s_sleep(1);
                }
            }
        }
        __syncthreads();
    }
}

// ---------------- host launch ----------------
extern "C" void kernel_launch(void* const* d_in, const int* in_sizes, int n_in,
                              void* d_out, int out_size, void* d_ws, size_t ws_size,
                              hipStream_t stream) {
    const float* x       = (const float*)d_in[0];
    const float* ih_vals = (const float*)d_in[1];
    const float* hh_vals = (const float*)d_in[2];
    const float* hh_bias = (const float*)d_in[3];
    const int*   ih_rows = (const int*)d_in[4];
    const int*   ih_cols = (const int*)d_in[5];
    const int*   hh_rows = (const int*)d_in[6];
    const int*   hh_cols = (const int*)d_in[7];
    float* out = (float*)d_out;

    const int nnz_ih = in_sizes[1];
    const int nnz_hh = in_sizes[2];

    char* ws = (char*)d_ws;
    size_t off = 0;
    auto alloc = [&](size_t bytes) -> void* {
        off = (off + 255) & ~(size_t)255;
        void* p = ws + off;
        off += bytes;
        return p;
    };

    unsigned short* xT2 = (unsigned short*)alloc((size_t)T_ * 8 * I_ * 8 * sizeof(unsigned short));
    int*   ih_rp  = (int*)alloc((H_ + 1) * sizeof(int));
    int*   hh_rp  = (int*)alloc((H_ + 1) * sizeof(int));
    int*   hh_pcnt = (int*)alloc(H_ * sizeof(int));

    const int ZINTS = 4 * H_ + 64 + 8 * 32 + 8 * 32 + 8 + 64;
    int* zbase  = (int*)alloc((size_t)ZINTS * sizeof(int));
    int* ih_cnt = zbase;
    int* ih_cur = zbase + H_;
    int* hh_cnt = zbase + 2 * H_;
    int* hh_cur = zbase + 3 * H_;
    int* regcnt = zbase + 4 * H_;
    int* barcnt = regcnt + 64;
    int* bargen = barcnt + 8 * 32;
    int* owncnt = bargen + 8 * 32;
    int* owngrp = owncnt + 8;

    int2* ih_pack = (int2*)alloc((size_t)nnz_ih * sizeof(int2));
    size_t hh_pack_n = (size_t)2 * nnz_hh + 64;   // padded bound + prefetch slack
    unsigned int* hh_pack = (unsigned int*)alloc(hh_pack_n * sizeof(unsigned int));
    unsigned short* hg = (unsigned short*)alloc((size_t)XCDS * 2 * 2 * H_ * 4 * sizeof(unsigned short)); // 1 MB
    unsigned short* pre = (unsigned short*)alloc((size_t)16 * T_ * H_ * 4 * sizeof(unsigned short)); // 67 MB

    hipMemsetAsync(zbase, 0, (size_t)ZINTS * sizeof(int), stream);
    hipMemsetAsync(hg, 0, (size_t)XCDS * 2 * 2 * H_ * 4 * sizeof(unsigned short), stream);
    hipMemsetAsync(hh_pack, 0, hh_pack_n * sizeof(unsigned int), stream);

    transpose_x<<<dim3(I_ / 128, 8, T_), dim3(128, 8), 0, stream>>>(x, xT2);

    hist_rows<<<(nnz_ih + 255) / 256, 256, 0, stream>>>(ih_rows, nnz_ih, ih_cnt);
    scan_rows<<<1, 64, 0, stream>>>(ih_cnt, ih_rp, H_);
    scatter_pack<<<(nnz_ih + 255) / 256, 256, 0, stream>>>(ih_rows, ih_cols, ih_vals, nnz_ih,
                                                           ih_rp, ih_cur, ih_pack);
    hist_rows<<<(nnz_hh + 255) / 256, 256, 0, stream>>>(hh_rows, nnz_hh, hh_cnt);
    pad_counts<<<(H_ / 8 + 255) / 256, 256, 0, stream>>>(hh_cnt, hh_pcnt);
    scan_rows<<<1, 64, 0, stream>>>(hh_pcnt, hh_rp, H_);
    scatter_pack_bf16<<<(nnz_hh + 255) / 256, 256, 0, stream>>>(hh_rows, hh_cols, hh_vals,
                                                                nnz_hh, hh_rp, hh_cur, hh_pack);

    precompute_ih<<<dim3(H_ / 8 / 16, 8), dim3(1024), 0, stream>>>(xT2, ih_rp, ih_pack,
                                                                   hh_bias, pre);

    void* kargs[] = {
        (void*)&hh_rp, (void*)&hh_pack,
        (void*)&pre,
        (void*)&hg,
        (void*)&regcnt, (void*)&barcnt, (void*)&bargen,
        (void*)&owncnt, (void*)&owngrp,
        (void*)&out,
    };
    hipLaunchCooperativeKernel((const void*)rnn_steps, dim3(RNN_BLOCKS), dim3(RNN_THREADS),
                               kargs, 0, stream);
}

// Round 17
// 1288.948 us; speedup vs baseline: 1.1423x; 1.1013x over previous
//
#include <hip/hip_runtime.h>
#include <hip/hip_cooperative_groups.h>
#include <math.h>

namespace cg = cooperative_groups;

#define B_ 64
#define T_ 128
#define I_ 1024
#define H_ 4096
#define XCDS 8

#define RNN_BLOCKS 256
#define RNN_THREADS 1024

#define MAXIT_IH 8    // 64 nnz/row registerized (Poisson(32)); tail fallback beyond

// ---------------- helpers ----------------
__device__ __forceinline__ unsigned short f2bf(float f) {
    unsigned int u = __float_as_uint(f);
    unsigned int r = (u + 0x7fffu + ((u >> 16) & 1u)) >> 16;
    return (unsigned short)r;
}

__device__ __forceinline__ void load2x16_sc0(const void* p0, const void* p1,
                                             uint4& a, uint4& b) {
    asm volatile(
        "global_load_dwordx4 %0, %2, off sc0\n\t"
        "global_load_dwordx4 %1, %3, off sc0\n\t"
        "s_waitcnt vmcnt(0)"
        : "=&v"(a), "=&v"(b)
        : "v"(p0), "v"(p1));
}

// ---------------- transpose x (B,T,I) -> xT2 (T, 8, I, 8) bf16 ----------------
__global__ void transpose_x(const float* __restrict__ x, unsigned short* __restrict__ xT2) {
    __shared__ float lds[8][129];
    int t  = blockIdx.z;
    int bg = blockIdx.y;
    int i0 = blockIdx.x * 128;
    int tx = threadIdx.x;   // 0..127
    int ty = threadIdx.y;   // 0..7
    int b = bg * 8 + ty;
    lds[ty][tx] = x[(size_t)b * T_ * I_ + (size_t)t * I_ + i0 + tx];
    __syncthreads();
    int n  = ty * 128 + tx;
    int ii = n >> 3;
    int bs = n & 7;
    xT2[(((size_t)t * 8 + bg) * I_ + i0 + ii) * 8 + bs] = f2bf(lds[bs][ii]);
}

// ---------------- CSR build ----------------
__global__ void hist_rows(const int* __restrict__ rows, int nnz, int* __restrict__ counts) {
    int k = blockIdx.x * blockDim.x + threadIdx.x;
    if (k < nnz) atomicAdd(&counts[rows[k]], 1);
}

// pad each group-of-8 rows to (group max rounded up to 8): uniform len, no guards
__global__ void pad_counts(const int* __restrict__ cnt, int* __restrict__ pcnt) {
    int grp = blockIdx.x * blockDim.x + threadIdx.x;
    if (grp >= H_ / 8) return;
    int m = 0;
    #pragma unroll
    for (int j = 0; j < 8; ++j) m = max(m, cnt[grp * 8 + j]);
    m = (m + 7) & ~7;
    #pragma unroll
    for (int j = 0; j < 8; ++j) pcnt[grp * 8 + j] = m;
}

__global__ void scan_rows(const int* __restrict__ counts, int* __restrict__ rp, int n) {
    int lane = threadIdx.x;      // 0..63
    int chunk = n / 64;
    int base = lane * chunk;
    int s = 0;
    for (int j = 0; j < chunk; ++j) s += counts[base + j];
    int pre = s;
    for (int off = 1; off < 64; off <<= 1) {
        int up = __shfl_up(pre, off, 64);
        if (lane >= off) pre += up;
    }
    int run = pre - s;
    for (int j = 0; j < chunk; ++j) { rp[base + j] = run; run += counts[base + j]; }
    if (lane == 63) rp[n] = run;
}

__global__ void scatter_pack(const int* __restrict__ rows, const int* __restrict__ cols,
                             const float* __restrict__ vals, int nnz,
                             const int* __restrict__ rp, int* __restrict__ cursor,
                             int2* __restrict__ pack) {
    int k = blockIdx.x * blockDim.x + threadIdx.x;
    if (k < nnz) {
        int r = rows[k];
        int pos = atomicAdd(&cursor[r], 1);
        pack[rp[r] + pos] = make_int2(cols[k], __float_as_int(vals[k]));
    }
}

// hh pack compressed to 4 B/nnz: (bf16(val) << 16) | col.  2.6 MB padded ->
// L2-resident per XCD.  val bits usable as f32 by AND.
__global__ void scatter_pack_bf16(const int* __restrict__ rows, const int* __restrict__ cols,
                                  const float* __restrict__ vals, int nnz,
                                  const int* __restrict__ rp, int* __restrict__ cursor,
                                  unsigned int* __restrict__ pack) {
    int k = blockIdx.x * blockDim.x + threadIdx.x;
    if (k < nnz) {
        int r = rows[k];
        int pos = atomicAdd(&cursor[r], 1);
        pack[rp[r] + pos] = ((unsigned int)f2bf(vals[k]) << 16) | (unsigned int)cols[k];
    }
}

// ---------------- kernel P: pre[t] = W_ih * x_t + bias  (bf16 out) ----------------
// r12 proven form: bf16 x, 16 waves share double-buffered staging,
// issue-early/write-late, one barrier/step, CSR slice registerized.
__global__ __launch_bounds__(1024)
void precompute_ih(const unsigned short* __restrict__ xT2,
                   const int* __restrict__ rp, const int2* __restrict__ pack,
                   const float* __restrict__ bias,
                   unsigned short* __restrict__ pre) {
    __shared__ __align__(16) unsigned short xs[2][I_ * 8];   // 2 x 16 KB double buffer
    int grp  = blockIdx.y;
    int wave = threadIdx.x >> 6;                  // 0..15
    int lane = threadIdx.x & 63;
    int rs = lane >> 3;   // row within group
    int u  = lane & 7;    // position within window

    int g = blockIdx.x * 16 + wave;               // 0..511
    int r = g * 8 + rs;
    int hb = rp[r];
    int len = rp[r + 1] - hb;
    int lm = len;
    lm = max(lm, __shfl_xor(lm, 8));
    lm = max(lm, __shfl_xor(lm, 16));
    lm = max(lm, __shfl_xor(lm, 32));
    int lmax = __builtin_amdgcn_readfirstlane(lm);
    float bsv = bias[r];

    // registerize the CSR slice (t-invariant): byte offsets pre-shifted
    int   pcol[MAXIT_IH];
    float pval[MAXIT_IH];
    #pragma unroll
    for (int it = 0; it < MAXIT_IH; ++it) {
        int2 pk = make_int2(0, 0);
        if (it * 8 + u < len) pk = pack[hb + it * 8 + u];
        pcol[it] = pk.x << 4;                 // col * 8 bf16 * 2 B
        pval[it] = __int_as_float(pk.y);
    }

    // prologue: stage t=0 into buffer 0
    {
        const uint4* s = (const uint4*)(xT2 + ((size_t)0 * 8 + grp) * (I_ * 8));
        ((uint4*)xs[0])[threadIdx.x] = s[threadIdx.x];   // 1024 x 16 B = 16 KB
    }
    __syncthreads();

    for (int t = 0; t < T_; ++t) {
        int cur = t & 1;

        // issue next step's staging load early (latency hides under compute)
        uint4 st0;
        bool havenext = (t + 1 < T_);
        if (havenext) {
            const uint4* s = (const uint4*)(xT2 + ((size_t)(t + 1) * 8 + grp) * (I_ * 8));
            st0 = s[threadIdx.x];
        }

        const char* xb = (const char*)xs[cur];
        float a[8];
        #pragma unroll
        for (int j = 0; j < 8; ++j) a[j] = 0.0f;

        // branchless registerized windows (padded lanes read col 0, add +0.0)
        #pragma unroll
        for (int it = 0; it < MAXIT_IH; ++it) {
            uint4 xw = *(const uint4*)(xb + pcol[it]);
            float v = pval[it];
            a[0] += v * __uint_as_float(xw.x << 16);
            a[1] += v * __uint_as_float(xw.x & 0xffff0000u);
            a[2] += v * __uint_as_float(xw.y << 16);
            a[3] += v * __uint_as_float(xw.y & 0xffff0000u);
            a[4] += v * __uint_as_float(xw.z << 16);
            a[5] += v * __uint_as_float(xw.z & 0xffff0000u);
            a[6] += v * __uint_as_float(xw.w << 16);
            a[7] += v * __uint_as_float(xw.w & 0xffff0000u);
        }
        if (lmax > 8 * MAXIT_IH) {   // rare tail, same summation order
            int kk = hb + 8 * MAXIT_IH + u;
            for (int i = 8 * MAXIT_IH; i < lmax; i += 8, kk += 8) {
                int2 pk = make_int2(0, 0);
                if (i + u < len) pk = pack[kk];
                uint4 xw = *(const uint4*)(xb + ((size_t)pk.x << 4));
                float v = __int_as_float(pk.y);
                a[0] += v * __uint_as_float(xw.x << 16);
                a[1] += v * __uint_as_float(xw.x & 0xffff0000u);
                a[2] += v * __uint_as_float(xw.y << 16);
                a[3] += v * __uint_as_float(xw.y & 0xffff0000u);
                a[4] += v * __uint_as_float(xw.z << 16);
                a[5] += v * __uint_as_float(xw.z & 0xffff0000u);
                a[6] += v * __uint_as_float(xw.w << 16);
                a[7] += v * __uint_as_float(xw.w & 0xffff0000u);
            }
        }
        #pragma unroll
        for (int off = 1; off <= 4; off <<= 1) {
            #pragma unroll
            for (int j = 0; j < 8; ++j) a[j] += __shfl_xor(a[j], off);
        }
        float sel = (u == 0) ? a[0] : (u == 1) ? a[1] : (u == 2) ? a[2] : (u == 3) ? a[3]
                  : (u == 4) ? a[4] : (u == 5) ? a[5] : (u == 6) ? a[6] : a[7];
        float p = sel + bsv;
        int hf = u >> 2, cc = u & 3;
        pre[((size_t)(grp * 2 + hf) * T_ + t) * (H_ * 4) + (size_t)r * 4 + cc] = f2bf(p);

        // write-late: commit next step's staging to the other buffer
        if (havenext) {
            ((uint4*)xs[cur ^ 1])[threadIdx.x] = st0;
        }
        __syncthreads();   // xs[cur^1] published; readers of xs[cur] done
    }
}

// ---------------- kernel R: persistent XCD-local recurrence ----------------
// r16 structure (bf16 state, padded guard-free CSR, compressed 4B hhpack,
// per-(xcd,half) barrier). Delta: each wave's TWO independent row-groups
// (g0=mywave, g1=mywave+nwh) computed as INTERLEAVED chains — two
// {pack, LDS-gather, FMA} dependency chains in flight halve effective
// per-window latency. Per-chain load/FMA order unchanged (bit-identical).
// hg layout: hg[((grp*2 + parity)*2 + half) * (H_*4)]  (ushort elements)
__global__ __launch_bounds__(RNN_THREADS, 1)
void rnn_steps(const int* __restrict__ hhp, const unsigned int* __restrict__ hhpack,
               const unsigned short* __restrict__ pre,
               unsigned short* __restrict__ hg,
               int* __restrict__ regcnt, int* __restrict__ barcnt, int* __restrict__ bargen,
               int* __restrict__ owncnt, int* __restrict__ owngrp,
               float* __restrict__ out) {
    cg::grid_group grid = cg::this_grid();
    __shared__ __align__(16) unsigned short sh[H_ * 4];   // 32 KB: bf16 h_prev
    __shared__ int meta[2];

    int tid = threadIdx.x;
    if (tid == 0) {
        int x;
        asm volatile("s_getreg_b32 %0, hwreg(HW_REG_XCC_ID)" : "=s"(x));
        x &= 7;
        int slot = __hip_atomic_fetch_add(&regcnt[x], 1, __ATOMIC_RELAXED,
                                          __HIP_MEMORY_SCOPE_AGENT);
        meta[0] = x;
        meta[1] = slot;
    }
    __syncthreads();
    int xcd  = meta[0];
    int slot = meta[1];
    grid.sync();

    if (blockIdx.x == 0 && tid == 0) {
        int list[XCDS]; int nz = 0;
        for (int j = 0; j < XCDS; ++j) {
            owncnt[j] = 0;
            if (__hip_atomic_load(&regcnt[j], __ATOMIC_RELAXED,
                                  __HIP_MEMORY_SCOPE_AGENT) > 0) list[nz++] = j;
        }
        int rr = 0;
        for (int j = 0; j < XCDS; ++j) {
            int present = __hip_atomic_load(&regcnt[j], __ATOMIC_RELAXED,
                                            __HIP_MEMORY_SCOPE_AGENT) > 0;
            int owner = present ? j : list[rr++ % nz];
            owngrp[owner * 8 + owncnt[owner]] = j;
            owncnt[owner] += 1;
        }
    }
    grid.sync();

    int nblk = __hip_atomic_load(&regcnt[xcd], __ATOMIC_RELAXED, __HIP_MEMORY_SCOPE_AGENT);
    int nown = owncnt[xcd];

    int wave = tid >> 6;
    int lane = tid & 63;
    int rs   = lane >> 3;
    int u    = lane & 7;

    // half assignment (robust to nblk==1)
    int hfbeg, hfend, mywave, nwh, myhf, hcnt;
    if (nblk >= 2) {
        int hf = slot & 1;
        hfbeg = hf; hfend = hf + 1;
        int nhb = (hf == 0) ? ((nblk + 1) >> 1) : (nblk >> 1);
        mywave = (slot >> 1) * (RNN_THREADS / 64) + wave;
        nwh = nhb * (RNN_THREADS / 64);
        myhf = hf; hcnt = nhb;
    } else {
        hfbeg = 0; hfend = 2;
        mywave = wave; nwh = RNN_THREADS / 64;
        myhf = 0; hcnt = 1;
    }

    // static pair of row-groups per wave (typical case: exactly 2)
    int g0 = mywave, g1 = mywave + nwh;
    bool valid0 = g0 < (H_ / 8), valid1 = g1 < (H_ / 8);
    int r0 = g0 * 8 + rs, r1 = g1 * 8 + rs;
    int hb0 = 0, len0 = 0, hb1 = 0, len1 = 0;
    if (valid0) { hb0 = hhp[r0]; len0 = hhp[r0 + 1] - hb0; }
    if (valid1) { hb1 = hhp[r1]; len1 = hhp[r1 + 1] - hb1; }
    int lenC = min(len0, len1);   // interleaved windows; tails sequential
    bool dyn = (mywave + 2 * nwh) < (H_ / 8);   // rare (uneven dispatch only)

    // per-(xcd, half) barrier state: 8-int (32 B) apart within the xcd's row
    int* bc   = &barcnt[xcd * 32 + myhf * 8];
    int* bgen = &bargen[xcd * 32 + myhf * 8];

    for (int t = 0; t < T_; ++t) {
        for (int oi = 0; oi < nown; ++oi) {
            int grp = owngrp[xcd * 8 + oi];
            for (int hf = hfbeg; hf < hfend; ++hf) {
                const unsigned short* src =
                    hg + (size_t)((grp * 2 + (t & 1)) * 2 + hf) * (H_ * 4);
                unsigned short* dst =
                    hg + (size_t)((grp * 2 + ((t + 1) & 1)) * 2 + hf) * (H_ * 4);
                const unsigned short* preb =
                    pre + ((size_t)(grp * 2 + hf) * T_ + t) * (H_ * 4);

                // early pre loads (u<8 index safe; consumed after reduce)
                unsigned short pus0 = 0, pus1 = 0;
                if (valid0) pus0 = preb[(size_t)r0 * 4 + u];
                if (valid1) pus1 = preb[(size_t)r1 * 4 + u];

                // ---- fill sh with bf16 h_prev (sc0: bypass stale L1, hit L2) ----
                __syncthreads();   // prior readers of sh are done
                {
                    uint4 v0, v1;
                    const char* s = (const char*)src;
                    load2x16_sc0(s + (size_t)tid * 16,
                                 s + (size_t)(1024 + tid) * 16, v0, v1);
                    uint4* s4 = (uint4*)sh;
                    s4[tid]        = v0;
                    s4[1024 + tid] = v1;
                }
                __syncthreads();   // sh ready

                // ---- compute: two interleaved independent window chains ----
                float a00 = 0.f, a01 = 0.f, a02 = 0.f, a03 = 0.f;
                float a10 = 0.f, a11 = 0.f, a12 = 0.f, a13 = 0.f;
                int kk0 = hb0 + u, kk1 = hb1 + u;
                unsigned int pk0 = hhpack[kk0];
                unsigned int pk1 = hhpack[kk1];
                int i = 0;
                for (; i < lenC; i += 8) {
                    kk0 += 8; kk1 += 8;
                    unsigned int pn0 = hhpack[kk0];
                    unsigned int pn1 = hhpack[kk1];
                    uint2 hw0 = *(const uint2*)((const char*)sh +
                                                ((size_t)(pk0 & 0xffffu) << 3));
                    uint2 hw1 = *(const uint2*)((const char*)sh +
                                                ((size_t)(pk1 & 0xffffu) << 3));
                    float v0 = __uint_as_float(pk0 & 0xffff0000u);
                    float v1 = __uint_as_float(pk1 & 0xffff0000u);
                    a00 += v0 * __uint_as_float(hw0.x << 16);
                    a01 += v0 * __uint_as_float(hw0.x & 0xffff0000u);
                    a02 += v0 * __uint_as_float(hw0.y << 16);
                    a03 += v0 * __uint_as_float(hw0.y & 0xffff0000u);
                    a10 += v1 * __uint_as_float(hw1.x << 16);
                    a11 += v1 * __uint_as_float(hw1.x & 0xffff0000u);
                    a12 += v1 * __uint_as_float(hw1.y << 16);
                    a13 += v1 * __uint_as_float(hw1.y & 0xffff0000u);
                    pk0 = pn0; pk1 = pn1;
                }
                for (int i0 = i; i0 < len0; i0 += 8) {   // chain-0 tail, same order
                    kk0 += 8;
                    unsigned int pn0 = hhpack[kk0];
                    uint2 hw0 = *(const uint2*)((const char*)sh +
                                                ((size_t)(pk0 & 0xffffu) << 3));
                    float v0 = __uint_as_float(pk0 & 0xffff0000u);
                    a00 += v0 * __uint_as_float(hw0.x << 16);
                    a01 += v0 * __uint_as_float(hw0.x & 0xffff0000u);
                    a02 += v0 * __uint_as_float(hw0.y << 16);
                    a03 += v0 * __uint_as_float(hw0.y & 0xffff0000u);
                    pk0 = pn0;
                }
                for (int i1 = i; i1 < len1; i1 += 8) {   // chain-1 tail, same order
                    kk1 += 8;
                    unsigned int pn1 = hhpack[kk1];
                    uint2 hw1 = *(const uint2*)((const char*)sh +
                                                ((size_t)(pk1 & 0xffffu) << 3));
                    float v1 = __uint_as_float(pk1 & 0xffff0000u);
                    a10 += v1 * __uint_as_float(hw1.x << 16);
                    a11 += v1 * __uint_as_float(hw1.x & 0xffff0000u);
                    a12 += v1 * __uint_as_float(hw1.y << 16);
                    a13 += v1 * __uint_as_float(hw1.y & 0xffff0000u);
                    pk1 = pn1;
                }
                #pragma unroll
                for (int off = 1; off <= 4; off <<= 1) {
                    a00 += __shfl_xor(a00, off);
                    a01 += __shfl_xor(a01, off);
                    a02 += __shfl_xor(a02, off);
                    a03 += __shfl_xor(a03, off);
                    a10 += __shfl_xor(a10, off);
                    a11 += __shfl_xor(a11, off);
                    a12 += __shfl_xor(a12, off);
                    a13 += __shfl_xor(a13, off);
                }
                if (u < 4) {
                    if (valid0) {
                        float acc = (u == 0) ? a00 : (u == 1) ? a01 : (u == 2) ? a02 : a03;
                        float pv = __uint_as_float((unsigned int)pus0 << 16);
                        float h = tanhf(acc + pv);
                        dst[(size_t)r0 * 4 + u] = f2bf(h);
                        int b = grp * 8 + hf * 4 + u;
                        out[(size_t)b * T_ * H_ + (size_t)t * H_ + r0] = h;
                    }
                    if (valid1) {
                        float acc = (u == 0) ? a10 : (u == 1) ? a11 : (u == 2) ? a12 : a13;
                        float pv = __uint_as_float((unsigned int)pus1 << 16);
                        float h = tanhf(acc + pv);
                        dst[(size_t)r1 * 4 + u] = f2bf(h);
                        int b = grp * 8 + hf * 4 + u;
                        out[(size_t)b * T_ * H_ + (size_t)t * H_ + r1] = h;
                    }
                }
                if (dyn) {   // rare: >2 row-groups/wave — single-chain fallback
                    for (int g = mywave + 2 * nwh; g < H_ / 8; g += nwh) {
                        int r  = g * 8 + rs;
                        int hb = hhp[r];
                        int len = hhp[r + 1] - hb;
                        unsigned short pus = preb[(size_t)r * 4 + u];
                        float a0 = 0.f, a1 = 0.f, a2 = 0.f, a3 = 0.f;
                        int kk = hb + u;
                        unsigned int pk = hhpack[kk];
                        for (int j = 0; j < len; j += 8) {
                            kk += 8;
                            unsigned int pkn = hhpack[kk];
                            uint2 hw = *(const uint2*)((const char*)sh +
                                                       ((size_t)(pk & 0xffffu) << 3));
                            float v = __uint_as_float(pk & 0xffff0000u);
                            a0 += v * __uint_as_float(hw.x << 16);
                            a1 += v * __uint_as_float(hw.x & 0xffff0000u);
                            a2 += v * __uint_as_float(hw.y << 16);
                            a3 += v * __uint_as_float(hw.y & 0xffff0000u);
                            pk = pkn;
                        }
                        #pragma unroll
                        for (int off = 1; off <= 4; off <<= 1) {
                            a0 += __shfl_xor(a0, off);
                            a1 += __shfl_xor(a1, off);
                            a2 += __shfl_xor(a2, off);
                            a3 += __shfl_xor(a3, off);
                        }
                        if (u < 4) {
                            float acc = (u == 0) ? a0 : (u == 1) ? a1 : (u == 2) ? a2 : a3;
                            float pv = __uint_as_float(
                                (unsigned int)pus << 16);
                            float h = tanhf(acc + pv);
                            dst[(size_t)r * 4 + u] = f2bf(h);
                            int b = grp * 8 + hf * 4 + u;
                            out[(size_t)b * T_ * H_ + (size_t)t * H_ + r] = h;
                        }
                    }
                }
            }
        }

        // ---- per-(xcd, half) barrier (r12's proven protocol, narrower group) ----
        __syncthreads();   // drains this block's h stores to L2 (vmcnt(0) before s_barrier)
        if (tid == 0) {
            asm volatile("s_waitcnt vmcnt(0)" ::: "memory");
            int target = t + 1;
            int old = __hip_atomic_fetch_add(bc, 1, __ATOMIC_RELAXED,
                                             __HIP_MEMORY_SCOPE_AGENT);
            if (old == hcnt - 1) {
                __hip_atomic_store(bc, 0, __ATOMIC_RELAXED, __HIP_MEMORY_SCOPE_AGENT);
                __hip_atomic_store(bgen, target, __ATOMIC_RELAXED, __HIP_MEMORY_SCOPE_AGENT);
            } else {
                while (__hip_atomic_load(bgen, __ATOMIC_RELAXED,
                                         __HIP_MEMORY_SCOPE_AGENT) < target) {
                    __builtin_amdgcn_s_sleep(1);
                }
            }
        }
        __syncthreads();
    }
}

// ---------------- host launch ----------------
extern "C" void kernel_launch(void* const* d_in, const int* in_sizes, int n_in,
                              void* d_out, int out_size, void* d_ws, size_t ws_size,
                              hipStream_t stream) {
    const float* x       = (const float*)d_in[0];
    const float* ih_vals = (const float*)d_in[1];
    const float* hh_vals = (const float*)d_in[2];
    const float* hh_bias = (const float*)d_in[3];
    const int*   ih_rows = (const int*)d_in[4];
    const int*   ih_cols = (const int*)d_in[5];
    const int*   hh_rows = (const int*)d_in[6];
    const int*   hh_cols = (const int*)d_in[7];
    float* out = (float*)d_out;

    const int nnz_ih = in_sizes[1];
    const int nnz_hh = in_sizes[2];

    char* ws = (char*)d_ws;
    size_t off = 0;
    auto alloc = [&](size_t bytes) -> void* {
        off = (off + 255) & ~(size_t)255;
        void* p = ws + off;
        off += bytes;
        return p;
    };

    unsigned short* xT2 = (unsigned short*)alloc((size_t)T_ * 8 * I_ * 8 * sizeof(unsigned short));
    int*   ih_rp  = (int*)alloc((H_ + 1) * sizeof(int));
    int*   hh_rp  = (int*)alloc((H_ + 1) * sizeof(int));
    int*   hh_pcnt = (int*)alloc(H_ * sizeof(int));

    const int ZINTS = 4 * H_ + 64 + 8 * 32 + 8 * 32 + 8 + 64;
    int* zbase  = (int*)alloc((size_t)ZINTS * sizeof(int));
    int* ih_cnt = zbase;
    int* ih_cur = zbase + H_;
    int* hh_cnt = zbase + 2 * H_;
    int* hh_cur = zbase + 3 * H_;
    int* regcnt = zbase + 4 * H_;
    int* barcnt = regcnt + 64;
    int* bargen = barcnt + 8 * 32;
    int* owncnt = bargen + 8 * 32;
    int* owngrp = owncnt + 8;

    int2* ih_pack = (int2*)alloc((size_t)nnz_ih * sizeof(int2));
    size_t hh_pack_n = (size_t)2 * nnz_hh + 64;   // padded bound + prefetch slack
    unsigned int* hh_pack = (unsigned int*)alloc(hh_pack_n * sizeof(unsigned int));
    unsigned short* hg = (unsigned short*)alloc((size_t)XCDS * 2 * 2 * H_ * 4 * sizeof(unsigned short)); // 1 MB
    unsigned short* pre = (unsigned short*)alloc((size_t)16 * T_ * H_ * 4 * sizeof(unsigned short)); // 67 MB

    hipMemsetAsync(zbase, 0, (size_t)ZINTS * sizeof(int), stream);
    hipMemsetAsync(hg, 0, (size_t)XCDS * 2 * 2 * H_ * 4 * sizeof(unsigned short), stream);
    hipMemsetAsync(hh_pack, 0, hh_pack_n * sizeof(unsigned int), stream);

    transpose_x<<<dim3(I_ / 128, 8, T_), dim3(128, 8), 0, stream>>>(x, xT2);

    hist_rows<<<(nnz_ih + 255) / 256, 256, 0, stream>>>(ih_rows, nnz_ih, ih_cnt);
    scan_rows<<<1, 64, 0, stream>>>(ih_cnt, ih_rp, H_);
    scatter_pack<<<(nnz_ih + 255) / 256, 256, 0, stream>>>(ih_rows, ih_cols, ih_vals, nnz_ih,
                                                           ih_rp, ih_cur, ih_pack);
    hist_rows<<<(nnz_hh + 255) / 256, 256, 0, stream>>>(hh_rows, nnz_hh, hh_cnt);
    pad_counts<<<(H_ / 8 + 255) / 256, 256, 0, stream>>>(hh_cnt, hh_pcnt);
    scan_rows<<<1, 64, 0, stream>>>(hh_pcnt, hh_rp, H_);
    scatter_pack_bf16<<<(nnz_hh + 255) / 256, 256, 0, stream>>>(hh_rows, hh_cols, hh_vals,
                                                                nnz_hh, hh_rp, hh_cur, hh_pack);

    precompute_ih<<<dim3(H_ / 8 / 16, 8), dim3(1024), 0, stream>>>(xT2, ih_rp, ih_pack,
                                                                   hh_bias, pre);

    void* kargs[] = {
        (void*)&hh_rp, (void*)&hh_pack,
        (void*)&pre,
        (void*)&hg,
        (void*)&regcnt, (void*)&barcnt, (void*)&bargen,
        (void*)&owncnt, (void*)&owngrp,
        (void*)&out,
    };
    hipLaunchCooperativeKernel((const void*)rnn_steps, dim3(RNN_BLOCKS), dim3(RNN_THREADS),
                               kargs, 0, stream);
}